// Round 13
// baseline (155.775 us; speedup 1.0000x reference)
//
#include <hip/hip_runtime.h>

#define SEQ 4096
#define EMB 1024
#define HS 64

typedef __attribute__((ext_vector_type(8))) short bf16x8;
typedef __attribute__((ext_vector_type(4))) float f32x4;

__device__ __forceinline__ unsigned short f2b(float f) {
    union { float f; unsigned u; } v; v.f = f;
    unsigned r = v.u + 0x7fffu + ((v.u >> 16) & 1u);
    return (unsigned short)(r >> 16);
}
__device__ __forceinline__ float b2f(unsigned short h) {
    union { unsigned u; float f; } v; v.u = ((unsigned)h) << 16;
    return v.f;
}
// async global->LDS DMA, 16B/lane; LDS dst = wave-uniform base + lane*16
template <typename T>
__device__ __forceinline__ void gll16(const T* g, void* l) {
    __builtin_amdgcn_global_load_lds(
        (const __attribute__((address_space(1))) unsigned int*)(g),
        (__attribute__((address_space(3))) unsigned int*)(l), 16, 0, 0);
}

// ---------- W transpose + cast: Wt[192][1024] bf16; rows 0-63=Q (pre-scaled), 64-127=K, 128-191=V
__global__ __launch_bounds__(256) void wt_kernel(const float* __restrict__ Wq,
                                                 const float* __restrict__ Wk,
                                                 const float* __restrict__ Wv,
                                                 unsigned short* __restrict__ Wt) {
    int id = blockIdx.x * 256 + threadIdx.x;
    int mat = id >> 16;
    int rem = id & 65535;
    int k = rem >> 6;
    int n = rem & 63;
    const float* W = (mat == 0) ? Wq : (mat == 1) ? Wk : Wv;
    float scale = (mat == 0) ? 0.125f * 1.44269504f : 1.0f;   // fold 1/sqrt(64)*log2(e) into Q
    Wt[(mat * HS + n) * EMB + k] = f2b(W[k * HS + n] * scale);
}

// ---------- fused QKV projection v5: 32 rows x 96 cols per block, 2 N-classes, 4 blocks/CU ----------
// grid 1024 = 512 row-tiles x 2 classes; LDS 40KB -> exactly 4 blocks/CU, 16 waves/CU
__global__ __launch_bounds__(256, 4) void proj_kernel(const float* __restrict__ x,
                                                      const unsigned short* __restrict__ Wt,
                                                      unsigned short* __restrict__ Qb,
                                                      unsigned short* __restrict__ Kb,
                                                      unsigned short* __restrict__ Vt) {
    __shared__ float xf[2][32 * 64];              // 2 x 8 KiB, chunk swizzle c^(row&15)
    __shared__ unsigned short wb[2][96 * 64];     // 2 x 12 KiB, chunk swizzle c^(row&7)
    const int tid = threadIdx.x;
    const int wave = tid >> 6, lane = tid & 63;
    const int col = lane & 15, quad = lane >> 4;
    const int bid = blockIdx.x;
    const int cls = bid & 1;                      // N-class: cols [cls*96, cls*96+96)
    const int m0 = (bid >> 1) * 32;
    const int b = m0 >> 12, t0 = m0 & 4095;
    const int mh = wave & 1;                      // m-half: 16 rows
    const int ngrp = wave >> 1;                   // n-group: 48 local cols

    const int xr_in = lane >> 4;
    const int xc = lane & 15;
    const int wr_in = lane >> 3;
    const int wc = lane & 7;

    f32x4 acc[3];
    #pragma unroll
    for (int j = 0; j < 3; j++) acc[j] = (f32x4){0.f, 0.f, 0.f, 0.f};

    auto stage = [&](int k0, int bufi) {
        #pragma unroll
        for (int t = 0; t < 2; t++) {
            int R = (wave + t * 4) * 4;            // x rows R..R+3
            int row = R + xr_in;
            gll16(x + (size_t)(m0 + row) * EMB + k0 + ((xc ^ (row & 15)) << 2),
                  &xf[bufi][R * 64]);
        }
        #pragma unroll
        for (int t = 0; t < 3; t++) {
            int R = (wave * 3 + t) * 8;            // W local rows R..R+7
            int row = R + wr_in;
            gll16(Wt + (size_t)(cls * 96 + row) * EMB + k0 + ((wc ^ (row & 7)) << 3),
                  &wb[bufi][R * 64]);
        }
    };

    stage(0, 0);
    int buf = 0;
    #pragma unroll 1
    for (int k0 = 0; k0 < EMB; k0 += 64) {
        __syncthreads();                 // DMA(buf) landed; prev readers of buf^1 done
        if (k0 + 64 < EMB) stage(k0 + 64, buf ^ 1);
        #pragma unroll
        for (int kc = 0; kc < 2; kc++) {
            const int q2 = quad + kc * 4;
            const int rr = mh * 16 + col;
            float4 lo = *(const float4*)&xf[buf][rr * 64 + (((2 * q2) ^ col) << 2)];
            float4 hi = *(const float4*)&xf[buf][rr * 64 + (((2 * q2 + 1) ^ col) << 2)];
            bf16x8 af;
            af[0] = (short)f2b(lo.x); af[1] = (short)f2b(lo.y);
            af[2] = (short)f2b(lo.z); af[3] = (short)f2b(lo.w);
            af[4] = (short)f2b(hi.x); af[5] = (short)f2b(hi.y);
            af[6] = (short)f2b(hi.z); af[7] = (short)f2b(hi.w);
            #pragma unroll
            for (int nt = 0; nt < 3; nt++) {
                int rn = ngrp * 48 + nt * 16 + col;    // rn&7 == col&7
                bf16x8 bfr = *(const bf16x8*)&wb[buf][rn * 64 + ((q2 ^ (col & 7)) << 3)];
                acc[nt] = __builtin_amdgcn_mfma_f32_16x16x32_bf16(af, bfr, acc[nt], 0, 0, 0);
            }
        }
        buf ^= 1;
    }

    #pragma unroll
    for (int nt = 0; nt < 3; nt++) {
        const int G = cls * 96 + ngrp * 48 + nt * 16 + col;   // global output col 0..191
        const int mat = G >> 6;                                // 0=Q 1=K 2=V (tile-uniform)
        const int nc = G & 63;
        #pragma unroll
        for (int r = 0; r < 4; r++) {
            unsigned short val = f2b(acc[nt][r]);
            int row = mh * 16 + quad * 4 + r;
            if (mat == 0)      Qb[(size_t)(m0 + row) * HS + nc] = val;
            else if (mat == 1) Kb[(size_t)(m0 + row) * HS + nc] = val;
            else               Vt[((size_t)b * HS + nc) * SEQ + t0 + row] = val;
        }
    }
}

// ---------- flash attention (causal): 8-wave blocks, BM=128, dbuf DMA K/V (R12-proven) ----------
// tile T has 2T+2 kv-steps; pieces of <=12 steps; np(T)=(T+6)/6; grid 408 <= resident slots
__global__ __launch_bounds__(512, 4) void attn_kernel(const unsigned short* __restrict__ Qb,
                                                      const unsigned short* __restrict__ Kb,
                                                      const unsigned short* __restrict__ Vt,
                                                      unsigned short* __restrict__ Opart,
                                                      float* __restrict__ Lpart) {
    __shared__ unsigned short Kl[2][64 * 64];   // 2 x 8 KiB, chunk swizzle c^(row&7)
    __shared__ unsigned short Vl[2][64 * 64];   // 2 x 8 KiB, chunk swizzle c^(h&7)
    __shared__ unsigned short P_lds[8][16 * 72];
    const int tid = threadIdx.x;
    const int wave = tid >> 6, lane = tid & 63;
    const int col = lane & 15, quad = lane >> 4;
    const int bid = blockIdx.x;            // 0..407
    const int g = 101 - (bid >> 2);        // longest-first piece id
    const int b = bid & 3;
    // decode g -> (T, piece)
    int T = 0, accp = 0;
    for (;;) { int np = (T + 6) / 6; if (accp + np > g) break; accp += np; T++; }
    const int piece = g - accp;
    const int q0 = T << 7;
    const int s_beg = piece * 12;
    const int s_end = min(s_beg + 12, 2 * T + 2);

    const unsigned short* Kp = Kb + ((size_t)(b << 12)) * HS;
    const unsigned short* Vp = Vt + (size_t)b * HS * SEQ;

    bf16x8 qf[2];
    #pragma unroll
    for (int c = 0; c < 2; c++)
        qf[c] = *(const bf16x8*)(Qb + ((size_t)(b << 12) + q0 + wave * 16 + col) * HS + quad * 8 + c * 32);

    f32x4 o[4];
    float l[4];
    #pragma unroll
    for (int ct = 0; ct < 4; ct++) o[ct] = (f32x4){0.f, 0.f, 0.f, 0.f};
    #pragma unroll
    for (int r = 0; r < 4; r++) l[r] = 0.f;

    const int r_in = lane >> 3;   // 0..7 rows within one DMA instr
    const int ch = lane & 7;      // 16B chunk within 128B row

    auto stage = [&](int s, int bufi) {
        const int kv0 = s << 6;
        int R = wave * 8;
        int row = R + r_in;
        gll16(Kp + (size_t)(kv0 + row) * HS + ((ch ^ (row & 7)) << 3), &Kl[bufi][R * 64]);
        gll16(Vp + (size_t)row * SEQ + kv0 + ((ch ^ (row & 7)) << 3), &Vl[bufi][R * 64]);
    };

    stage(s_beg, 0);
    int buf = 0;
    const int rgb = q0 + wave * 16 + quad * 4;
    unsigned short* Pl = P_lds[wave];

    #pragma unroll 1
    for (int s = s_beg; s < s_end; s++) {
        __syncthreads();
        if (s + 1 < s_end) stage(s + 1, buf ^ 1);
        const int kv0 = s << 6;

        f32x4 sacc[4];
        #pragma unroll
        for (int ct = 0; ct < 4; ct++) sacc[ct] = (f32x4){0.f, 0.f, 0.f, 0.f};
        #pragma unroll
        for (int ct = 0; ct < 4; ct++) {
            int n = ct * 16 + col;
            #pragma unroll
            for (int kc = 0; kc < 2; kc++) {
                bf16x8 kf = *(const bf16x8*)&Kl[buf][n * 64 + (((kc * 4 + quad) ^ (col & 7)) << 3)];
                sacc[ct] = __builtin_amdgcn_mfma_f32_16x16x32_bf16(qf[kc], kf, sacc[ct], 0, 0, 0);
            }
        }

        float p[4][4];
        #pragma unroll
        for (int ct = 0; ct < 4; ct++) {
            int cg = kv0 + ct * 16 + col;
            #pragma unroll
            for (int r = 0; r < 4; r++) {
                float e = __builtin_exp2f(sacc[ct][r]);
                e = (cg > rgb + r) ? 0.f : e;
                p[ct][r] = e;
                l[r] += e;
            }
        }

        #pragma unroll
        for (int ct = 0; ct < 4; ct++)
            #pragma unroll
            for (int r = 0; r < 4; r++)
                Pl[(quad * 4 + r) * 72 + ct * 16 + col] = f2b(p[ct][r]);
        bf16x8 pf[2];
        #pragma unroll
        for (int c = 0; c < 2; c++)
            pf[c] = *(const bf16x8*)&Pl[col * 72 + quad * 8 + c * 32];

        #pragma unroll
        for (int ct = 0; ct < 4; ct++) {
            int h = ct * 16 + col;
            #pragma unroll
            for (int kc = 0; kc < 2; kc++) {
                bf16x8 vf = *(const bf16x8*)&Vl[buf][h * 64 + (((kc * 4 + quad) ^ (col & 7)) << 3)];
                o[ct] = __builtin_amdgcn_mfma_f32_16x16x32_bf16(pf[kc], vf, o[ct], 0, 0, 0);
            }
        }
        buf ^= 1;
    }

    #pragma unroll
    for (int off = 1; off < 16; off <<= 1)
        #pragma unroll
        for (int r = 0; r < 4; r++)
            l[r] += __shfl_xor(l[r], off, 64);

    const int widx = bid * 8 + wave;
    unsigned short* Op = Opart + (size_t)widx * 1024;
    #pragma unroll
    for (int ct = 0; ct < 4; ct++) {
        ushort4 st;
        st.x = f2b(o[ct][0]); st.y = f2b(o[ct][1]);
        st.z = f2b(o[ct][2]); st.w = f2b(o[ct][3]);
        *(ushort4*)(Op + ct * 256 + lane * 4) = st;
    }
    if (col == 0) {
        #pragma unroll
        for (int r = 0; r < 4; r++)
            Lpart[widx * 16 + quad * 4 + r] = l[r];
    }
}

// ---------- combine split-KV partials: thread layout mirrors attn lanes (coalesced ushort4 reads)
__global__ __launch_bounds__(256) void comb_kernel(const unsigned short* __restrict__ Opart,
                                                   const float* __restrict__ Lpart,
                                                   float* __restrict__ out) {
    const int bid = blockIdx.x;            // 1024 = 4 b x 32 T x 8 wave
    const int b = bid & 3;
    const int T = (bid >> 2) & 31;
    const int wave = bid >> 7;             // 0..7
    const int tid = threadIdx.x;
    const int lane = tid & 63, ct = tid >> 6;
    const int col = lane & 15, quad = lane >> 4;

    const int q = T / 6, r6 = T % 6;
    const int base = (q + 1) * (3 * q + r6);   // piece-id prefix for pieces of <=12 steps
    const int np = (T + 6) / 6;

    float acc[4] = {0.f, 0.f, 0.f, 0.f};
    float l[4] = {0.f, 0.f, 0.f, 0.f};
    for (int p = 0; p < np; p++) {
        int gg = base + p;
        int bidp = ((101 - gg) << 2) | b;
        int widx = bidp * 8 + wave;
        ushort4 v = *(const ushort4*)(Opart + (size_t)widx * 1024 + ct * 256 + lane * 4);
        acc[0] += b2f(v.x); acc[1] += b2f(v.y);
        acc[2] += b2f(v.z); acc[3] += b2f(v.w);
        #pragma unroll
        for (int r = 0; r < 4; r++)
            l[r] += Lpart[widx * 16 + quad * 4 + r];
    }
    const size_t rowb = (size_t)(b << 12) + (T << 7) + wave * 16 + quad * 4;
    #pragma unroll
    for (int r = 0; r < 4; r++)
        out[(rowb + r) * HS + ct * 16 + col] = acc[r] / l[r];
}

extern "C" void kernel_launch(void* const* d_in, const int* in_sizes, int n_in,
                              void* d_out, int out_size, void* d_ws, size_t ws_size,
                              hipStream_t stream) {
    const float* x  = (const float*)d_in[0];
    const float* Wk = (const float*)d_in[1];
    const float* Wq = (const float*)d_in[2];
    const float* Wv = (const float*)d_in[3];
    float* out = (float*)d_out;

    char* ws = (char*)d_ws;
    unsigned short* Wt = (unsigned short*)(ws);                 // 393216 B
    unsigned short* Qb = (unsigned short*)(ws + 393216);        // 2 MiB
    unsigned short* Kb = (unsigned short*)(ws + 2490368);       // 2 MiB
    unsigned short* Vt = (unsigned short*)(ws + 4587520);       // 2 MiB
    unsigned short* Opart = (unsigned short*)(ws + 6684672);    // 408*8*1024*2 = 6.68 MB
    float* Lpart          = (float*)(ws + 13369344);            // 408*8*16*4 = 208896 B

    wt_kernel<<<dim3(768), dim3(256), 0, stream>>>(Wq, Wk, Wv, Wt);
    proj_kernel<<<dim3(1024), dim3(256), 0, stream>>>(x, Wt, Qb, Kb, Vt);
    attn_kernel<<<dim3(408), dim3(512), 0, stream>>>(Qb, Kb, Vt, Opart, Lpart);
    comb_kernel<<<dim3(1024), dim3(256), 0, stream>>>(Opart, Lpart, out);
}